// Round 8
// baseline (787.687 us; speedup 1.0000x reference)
//
#include <hip/hip_runtime.h>

// VQ-VAE quantization: two-sweep bf16-MFMA prefilter + exact fp32 rescore.
// Round 8: occupancy attack. 8 waves/block x 512 codes/wave (32 waves/CU
// offered = HW max), r3's two-sweep structure: sweep1 = max-only (16 fmax
// epilogue, -h folded into MFMA C-init), cross-wave row-max -> global
// threshold; sweep2 = same MFMA + ballot-OR early-skip push (single branch
// per clean tile). Register depth-2 prefetch (no LDS staging). Exact fp32
// rescore + LDS atomicMin keyed (ordbits(dist)<<32|code) -> exact argmin,
// first-index ties (jnp.argmin semantics). DELTA=0.25 >= 2*worst bf16 err.

#define NPTS    65536
#define CDIM    64
#define KCODES  4096
#define WAVES   8
#define KPW     (KCODES / WAVES)   // 512 codes per wave
#define TILES   (KPW / 16)         // 32 tiles of 16 codes
#define LISTCAP 4096
#define DELTA   0.25f

typedef __attribute__((ext_vector_type(8))) short short8;
typedef __attribute__((ext_vector_type(4))) float f32x4;

__device__ __forceinline__ unsigned short f2bf(float x) {
    unsigned u = __float_as_uint(x);
    return (unsigned short)((u + 0x7FFFu + ((u >> 16) & 1u)) >> 16);  // RNE
}

// cb fp32 -> bf16 copy + h[k] = 0.5*||e_k||^2
__global__ __launch_bounds__(256) void vq_prep(const float* __restrict__ cb,
                                               short* __restrict__ cbb,
                                               float* __restrict__ h) {
    int k = blockIdx.x * 256 + threadIdx.x;
    const float4* p = reinterpret_cast<const float4*>(cb + (size_t)k * CDIM);
    float s0 = 0.f, s1 = 0.f, s2 = 0.f, s3 = 0.f;
#pragma unroll
    for (int i = 0; i < 16; i += 2) {
        float4 va = p[i], vb = p[i + 1];
        s0 = fmaf(va.x, va.x, s0); s1 = fmaf(va.y, va.y, s1);
        s2 = fmaf(va.z, va.z, s2); s3 = fmaf(va.w, va.w, s3);
        s0 = fmaf(vb.x, vb.x, s0); s1 = fmaf(vb.y, vb.y, s1);
        s2 = fmaf(vb.z, vb.z, s2); s3 = fmaf(vb.w, vb.w, s3);
        short8 o;
        o[0] = (short)f2bf(va.x); o[1] = (short)f2bf(va.y);
        o[2] = (short)f2bf(va.z); o[3] = (short)f2bf(va.w);
        o[4] = (short)f2bf(vb.x); o[5] = (short)f2bf(vb.y);
        o[6] = (short)f2bf(vb.z); o[7] = (short)f2bf(vb.w);
        *reinterpret_cast<short8*>(cbb + (size_t)k * CDIM + i * 4) = o;
    }
    h[k] = 0.5f * ((s0 + s1) + (s2 + s3));
}

__global__ __launch_bounds__(512, 8) void vq_main(const float* __restrict__ enc,
                                                  const float* __restrict__ cbf,
                                                  const short* __restrict__ cbb,
                                                  const float* __restrict__ h,
                                                  float* __restrict__ out) {
    __shared__ unsigned list[LISTCAP];
    __shared__ float rowmax[WAVES][64];
    __shared__ float thrL[64];
    __shared__ unsigned long long mkey[64];
    __shared__ unsigned lcnt;

    const int tid  = threadIdx.x;
    const int wid  = tid >> 6, lane = tid & 63;
    const int lrow = lane & 15, lseg = lane >> 4;
    const int pbase = blockIdx.x * 64;     // 64 points per block
    const int k0 = wid * KPW;              // this wave's 512-code slice

    if (tid == 0) lcnt = 0;
    if (tid < 64) mkey[tid] = ~0ull;

    // ---- A fragments: the block's 64 points as bf16 (all waves identical) ----
    // 16x16x32 A layout: row = lane&15, k = (lane>>4)*8 + e (+32 per kk)
    short8 afr[4][2];
#pragma unroll
    for (int rt = 0; rt < 4; ++rt)
#pragma unroll
        for (int kk = 0; kk < 2; ++kk) {
            const float4* xp = reinterpret_cast<const float4*>(
                enc + (size_t)(pbase + rt * 16 + lrow) * CDIM + kk * 32 + lseg * 8);
            float4 v0 = xp[0], v1 = xp[1];
            short8 a;
            a[0] = (short)f2bf(v0.x); a[1] = (short)f2bf(v0.y);
            a[2] = (short)f2bf(v0.z); a[3] = (short)f2bf(v0.w);
            a[4] = (short)f2bf(v1.x); a[5] = (short)f2bf(v1.y);
            a[6] = (short)f2bf(v1.z); a[7] = (short)f2bf(v1.w);
            afr[rt][kk] = a;
        }
    __syncthreads();   // lcnt/mkey init visible before any push

    auto loadB = [&](int ct, short8& x0, short8& x1, float& hh) {
        int code = k0 + ct * 16 + lrow;
        const short* base = cbb + (size_t)code * CDIM + lseg * 8;
        x0 = *reinterpret_cast<const short8*>(base);
        x1 = *reinterpret_cast<const short8*>(base + 32);
        hh = h[code];
    };

    // MFMA body: acc = A.B - h (h folded into C-init)
    auto mfmaT = [&](const short8& b0, const short8& b1, float hc, f32x4* acc) {
#pragma unroll
        for (int rt = 0; rt < 4; ++rt) { acc[rt][0] = -hc; acc[rt][1] = -hc; acc[rt][2] = -hc; acc[rt][3] = -hc; }
#pragma unroll
        for (int rt = 0; rt < 4; ++rt)
            acc[rt] = __builtin_amdgcn_mfma_f32_16x16x32_bf16(afr[rt][0], b0, acc[rt], 0, 0, 0);
#pragma unroll
        for (int rt = 0; rt < 4; ++rt)
            acc[rt] = __builtin_amdgcn_mfma_f32_16x16x32_bf16(afr[rt][1], b1, acc[rt], 0, 0, 0);
    };

    // ---- sweep 1: pure row-max (16 fmax per tile), depth-2 prefetch ----
    f32x4 best[4];
#pragma unroll
    for (int rt = 0; rt < 4; ++rt)
#pragma unroll
        for (int i = 0; i < 4; ++i) best[rt][i] = -__builtin_inff();

    {
        short8 s0b0, s0b1, s1b0, s1b1; float s0h, s1h;
        loadB(0, s0b0, s0b1, s0h);
        loadB(1, s1b0, s1b1, s1h);
        for (int ct = 0; ct < TILES; ct += 2) {
            short8 n0, n1; float nh2;
            loadB(ct + 2 < TILES ? ct + 2 : 0, n0, n1, nh2);
            {
                f32x4 acc[4];
                mfmaT(s0b0, s0b1, s0h, acc);
#pragma unroll
                for (int rt = 0; rt < 4; ++rt)
#pragma unroll
                    for (int i = 0; i < 4; ++i) best[rt][i] = fmaxf(best[rt][i], acc[rt][i]);
            }
            s0b0 = n0; s0b1 = n1; s0h = nh2;
            loadB(ct + 3 < TILES ? ct + 3 : 0, n0, n1, nh2);
            {
                f32x4 acc[4];
                mfmaT(s1b0, s1b1, s1h, acc);
#pragma unroll
                for (int rt = 0; rt < 4; ++rt)
#pragma unroll
                    for (int i = 0; i < 4; ++i) best[rt][i] = fmaxf(best[rt][i], acc[rt][i]);
            }
            s1b0 = n0; s1b1 = n1; s1h = nh2;
        }
    }

    // intra-wave max over the 16 col-lanes
#pragma unroll
    for (int m = 1; m <= 8; m <<= 1)
#pragma unroll
        for (int rt = 0; rt < 4; ++rt)
#pragma unroll
            for (int i = 0; i < 4; ++i)
                best[rt][i] = fmaxf(best[rt][i], __shfl_xor(best[rt][i], m, 64));
    // lanes lrow==0 (lanes 0,16,32,48) cover all 64 rows
    if (lrow == 0) {
#pragma unroll
        for (int rt = 0; rt < 4; ++rt)
#pragma unroll
            for (int i = 0; i < 4; ++i)
                rowmax[wid][rt * 16 + lseg * 4 + i] = best[rt][i];
    }
    __syncthreads();
    if (tid < 64) {   // global row max across the 8 waves -> threshold
        float m = rowmax[0][tid];
#pragma unroll
        for (int w = 1; w < WAVES; ++w) m = fmaxf(m, rowmax[w][tid]);
        thrL[tid] = m - DELTA;
    }
    __syncthreads();

    f32x4 thr[4];
#pragma unroll
    for (int rt = 0; rt < 4; ++rt)
#pragma unroll
        for (int i = 0; i < 4; ++i) thr[rt][i] = thrL[rt * 16 + lseg * 4 + i];

    // ---- sweep 2: same MFMA; ballot-OR early-skip push ----
    {
        short8 s0b0, s0b1, s1b0, s1b1; float s0h, s1h;
        loadB(0, s0b0, s0b1, s0h);
        loadB(1, s1b0, s1b1, s1h);
        for (int ct = 0; ct < TILES; ct += 2) {
            short8 n0, n1; float nh2;
            loadB(ct + 2 < TILES ? ct + 2 : 0, n0, n1, nh2);
            {
                f32x4 acc[4];
                mfmaT(s0b0, s0b1, s0h, acc);
                unsigned long long any = 0ull;
#pragma unroll
                for (int rt = 0; rt < 4; ++rt)
#pragma unroll
                    for (int i = 0; i < 4; ++i) any |= __ballot(acc[rt][i] >= thr[rt][i]);
                if (any) {
                    unsigned code = (unsigned)(k0 + ct * 16 + lrow);
#pragma unroll
                    for (int rt = 0; rt < 4; ++rt)
#pragma unroll
                        for (int i = 0; i < 4; ++i)
                            if (acc[rt][i] >= thr[rt][i]) {
                                unsigned row = (unsigned)(rt * 16 + lseg * 4 + i);  // C/D row map (m89)
                                unsigned pos = atomicAdd(&lcnt, 1u);
                                if (pos < LISTCAP) list[pos] = (row << 12) | code;
                            }
                }
            }
            s0b0 = n0; s0b1 = n1; s0h = nh2;
            loadB(ct + 3 < TILES ? ct + 3 : 0, n0, n1, nh2);
            {
                f32x4 acc[4];
                mfmaT(s1b0, s1b1, s1h, acc);
                unsigned long long any = 0ull;
#pragma unroll
                for (int rt = 0; rt < 4; ++rt)
#pragma unroll
                    for (int i = 0; i < 4; ++i) any |= __ballot(acc[rt][i] >= thr[rt][i]);
                if (any) {
                    unsigned code = (unsigned)(k0 + (ct + 1) * 16 + lrow);
#pragma unroll
                    for (int rt = 0; rt < 4; ++rt)
#pragma unroll
                        for (int i = 0; i < 4; ++i)
                            if (acc[rt][i] >= thr[rt][i]) {
                                unsigned row = (unsigned)(rt * 16 + lseg * 4 + i);
                                unsigned pos = atomicAdd(&lcnt, 1u);
                                if (pos < LISTCAP) list[pos] = (row << 12) | code;
                            }
                }
            }
            s1b0 = n0; s1b1 = n1; s1h = nh2;
        }
    }
    __syncthreads();

    // ---- exact fp32 rescore: 4 lanes per candidate (coalesced 256B) ----
    unsigned cnt = lcnt; if (cnt > LISTCAP) cnt = LISTCAP;
    for (unsigned t4 = tid; t4 < cnt * 4; t4 += 512) {
        unsigned t = t4 >> 2; int q = t4 & 3;
        unsigned e = list[t];
        int row = (int)(e >> 12), c = (int)(e & 4095u);
        const float4* xp = reinterpret_cast<const float4*>(enc + (size_t)(pbase + row) * CDIM) + q * 4;
        const float4* ep = reinterpret_cast<const float4*>(cbf + (size_t)c * CDIM) + q * 4;
        float a0 = 0.f, a1 = 0.f, a2 = 0.f, a3 = 0.f;
#pragma unroll
        for (int i = 0; i < 4; ++i) {
            float4 xv = xp[i], ev = ep[i];
            a0 = fmaf(xv.x, ev.x, a0); a1 = fmaf(xv.y, ev.y, a1);
            a2 = fmaf(xv.z, ev.z, a2); a3 = fmaf(xv.w, ev.w, a3);
        }
        float p = (a0 + a1) + (a2 + a3);
        p += __shfl_xor(p, 1, 64);
        p += __shfl_xor(p, 2, 64);               // full dot in all 4 lanes
        if (q == 0) {
            float d2 = fmaf(-2.f, p, 2.f * h[c]);     // esq - 2*dot (bit-identical everywhere)
            unsigned bb = __float_as_uint(d2);
            unsigned ord = bb ^ (unsigned)(((int)bb >> 31) | 0x80000000);  // monotonic
            atomicMin(&mkey[row], ((unsigned long long)ord << 32) | (unsigned)c);
        }
    }
    __syncthreads();

    // ---- finalize: gather winner rows (8 threads per point) + idx ----
    {
        int p = tid >> 3, q = tid & 7;
        int c = (int)(mkey[p] & 4095u);
        const float4* ep = reinterpret_cast<const float4*>(cbf + (size_t)c * CDIM);
        float4* op = reinterpret_cast<float4*>(out + (size_t)(pbase + p) * CDIM);
        op[q] = ep[q];
        op[q + 8] = ep[q + 8];
        if (tid < 64)
            out[(size_t)NPTS * CDIM + pbase + tid] = (float)(mkey[tid] & 4095u);
    }
}

extern "C" void kernel_launch(void* const* d_in, const int* in_sizes, int n_in,
                              void* d_out, int out_size, void* d_ws, size_t ws_size,
                              hipStream_t stream) {
    const float* enc = (const float*)d_in[0];
    const float* cb  = (const float*)d_in[1];
    float* out = (float*)d_out;

    // ws: cbb bf16[4096*64] (512KB) | h fp32[4096] (16KB)
    short* cbb = (short*)d_ws;
    float* hws = (float*)(cbb + (size_t)KCODES * CDIM);

    vq_prep<<<KCODES / 256, 256, 0, stream>>>(cb, cbb, hws);
    vq_main<<<NPTS / 64, 512, 0, stream>>>(enc, cb, cbb, hws, out);
}

// Round 9
// 156.437 us; speedup vs baseline: 5.0352x; 5.0352x over previous
//
#include <hip/hip_runtime.h>

// VQ-VAE quantization: two-sweep bf16-MFMA prefilter + exact fp32 rescore.
// Round 9: r3 structure (best: 199us) + cheap sweep-2 gate + depth-4 prefetch.
//   sweep1: per-wave row max (16 fmax/tile, -h folded into MFMA C-init)
//           -> cross-wave LDS max -> global per-row threshold (max - DELTA)
//   sweep2: same MFMA; d[e]=acc-thr, v_max3 tree + one __ballot ->
//           single wave-uniform branch skips all 16 push regions on clean
//           tiles (~50%); dirty tiles do per-element pushes.
//   rescore: exact fp32 distance (4 lanes/cand), LDS atomicMin on
//            (ordbits(dist)<<32|code) -> exact argmin, first-index ties.
// DELTA=0.25 >= 2x worst bf16 dot error (~0.06) -> true winner always kept.

#define NPTS    65536
#define CDIM    64
#define KCODES  4096
#define WAVES   4
#define KPW     (KCODES / WAVES)   // 1024 codes per wave
#define TILES   (KPW / 16)         // 64 tiles of 16 codes
#define LISTCAP 4096
#define DELTA   0.25f

typedef __attribute__((ext_vector_type(8))) short short8;
typedef __attribute__((ext_vector_type(4))) float f32x4;

__device__ __forceinline__ unsigned short f2bf(float x) {
    unsigned u = __float_as_uint(x);
    return (unsigned short)((u + 0x7FFFu + ((u >> 16) & 1u)) >> 16);  // RNE
}

struct BT { short8 b0, b1; float hh; };

// cb fp32 -> bf16 copy + h[k] = 0.5*||e_k||^2
__global__ __launch_bounds__(256) void vq_prep(const float* __restrict__ cb,
                                               short* __restrict__ cbb,
                                               float* __restrict__ h) {
    int k = blockIdx.x * 256 + threadIdx.x;
    const float4* p = reinterpret_cast<const float4*>(cb + (size_t)k * CDIM);
    float s0 = 0.f, s1 = 0.f, s2 = 0.f, s3 = 0.f;
#pragma unroll
    for (int i = 0; i < 16; i += 2) {
        float4 va = p[i], vb = p[i + 1];
        s0 = fmaf(va.x, va.x, s0); s1 = fmaf(va.y, va.y, s1);
        s2 = fmaf(va.z, va.z, s2); s3 = fmaf(va.w, va.w, s3);
        s0 = fmaf(vb.x, vb.x, s0); s1 = fmaf(vb.y, vb.y, s1);
        s2 = fmaf(vb.z, vb.z, s2); s3 = fmaf(vb.w, vb.w, s3);
        short8 o;
        o[0] = (short)f2bf(va.x); o[1] = (short)f2bf(va.y);
        o[2] = (short)f2bf(va.z); o[3] = (short)f2bf(va.w);
        o[4] = (short)f2bf(vb.x); o[5] = (short)f2bf(vb.y);
        o[6] = (short)f2bf(vb.z); o[7] = (short)f2bf(vb.w);
        *reinterpret_cast<short8*>(cbb + (size_t)k * CDIM + i * 4) = o;
    }
    h[k] = 0.5f * ((s0 + s1) + (s2 + s3));
}

__global__ __launch_bounds__(256) void vq_main(const float* __restrict__ enc,
                                               const float* __restrict__ cbf,
                                               const short* __restrict__ cbb,
                                               const float* __restrict__ h,
                                               float* __restrict__ out) {
    __shared__ unsigned list[LISTCAP];
    __shared__ float rowmax[WAVES][64];
    __shared__ float thrL[64];
    __shared__ unsigned long long mkey[64];
    __shared__ unsigned lcnt;

    const int tid  = threadIdx.x;
    const int wid  = tid >> 6, lane = tid & 63;
    const int lrow = lane & 15, lseg = lane >> 4;
    const int pbase = blockIdx.x * 64;     // 64 points per block
    const int k0 = wid * KPW;              // this wave's 1024-code slice

    if (tid == 0) lcnt = 0;
    if (tid < 64) mkey[tid] = ~0ull;

    // ---- A fragments: the block's 64 points as bf16 ----
    // 16x16x32 A layout: row = lane&15, k = (lane>>4)*8 + e (+32 per kk)
    short8 afr[4][2];
#pragma unroll
    for (int rt = 0; rt < 4; ++rt)
#pragma unroll
        for (int kk = 0; kk < 2; ++kk) {
            const float4* xp = reinterpret_cast<const float4*>(
                enc + (size_t)(pbase + rt * 16 + lrow) * CDIM + kk * 32 + lseg * 8);
            float4 v0 = xp[0], v1 = xp[1];
            short8 a;
            a[0] = (short)f2bf(v0.x); a[1] = (short)f2bf(v0.y);
            a[2] = (short)f2bf(v0.z); a[3] = (short)f2bf(v0.w);
            a[4] = (short)f2bf(v1.x); a[5] = (short)f2bf(v1.y);
            a[6] = (short)f2bf(v1.z); a[7] = (short)f2bf(v1.w);
            afr[rt][kk] = a;
        }
    __syncthreads();   // lcnt/mkey init visible before any push

    auto loadB = [&](int ct, BT& s) {
        int code = k0 + ct * 16 + lrow;
        const short* base = cbb + (size_t)code * CDIM + lseg * 8;
        s.b0 = *reinterpret_cast<const short8*>(base);
        s.b1 = *reinterpret_cast<const short8*>(base + 32);
        s.hh = h[code];
    };

    // MFMA body: acc = A.B - h (h folded into C-init)
    auto mfmaT = [&](const BT& s, f32x4* acc) {
        float nh = -s.hh;
#pragma unroll
        for (int rt = 0; rt < 4; ++rt) { acc[rt][0] = nh; acc[rt][1] = nh; acc[rt][2] = nh; acc[rt][3] = nh; }
#pragma unroll
        for (int rt = 0; rt < 4; ++rt)
            acc[rt] = __builtin_amdgcn_mfma_f32_16x16x32_bf16(afr[rt][0], s.b0, acc[rt], 0, 0, 0);
#pragma unroll
        for (int rt = 0; rt < 4; ++rt)
            acc[rt] = __builtin_amdgcn_mfma_f32_16x16x32_bf16(afr[rt][1], s.b1, acc[rt], 0, 0, 0);
    };

    // ---- sweep 1: pure row-max, depth-4 prefetch (4-unrolled, static slots) ----
    f32x4 best[4];
#pragma unroll
    for (int rt = 0; rt < 4; ++rt)
#pragma unroll
        for (int i = 0; i < 4; ++i) best[rt][i] = -__builtin_inff();

    {
        BT s0, s1, s2, s3;
        loadB(0, s0); loadB(1, s1); loadB(2, s2); loadB(3, s3);
#define S1BODY(SLOT, T)                                                        \
        {                                                                      \
            f32x4 acc[4];                                                      \
            mfmaT(SLOT, acc);                                                  \
            _Pragma("unroll")                                                  \
            for (int rt = 0; rt < 4; ++rt)                                     \
                _Pragma("unroll")                                              \
                for (int i = 0; i < 4; ++i)                                    \
                    best[rt][i] = fmaxf(best[rt][i], acc[rt][i]);              \
            loadB((T) + 4 < TILES ? (T) + 4 : 0, SLOT);                        \
        }
        for (int t = 0; t < TILES; t += 4) {
            S1BODY(s0, t + 0)
            S1BODY(s1, t + 1)
            S1BODY(s2, t + 2)
            S1BODY(s3, t + 3)
        }
#undef S1BODY
    }

    // intra-wave max over the 16 col-lanes
#pragma unroll
    for (int m = 1; m <= 8; m <<= 1)
#pragma unroll
        for (int rt = 0; rt < 4; ++rt)
#pragma unroll
            for (int i = 0; i < 4; ++i)
                best[rt][i] = fmaxf(best[rt][i], __shfl_xor(best[rt][i], m, 64));
    if (lrow == 0) {   // lanes 0,16,32,48 cover all 64 rows
#pragma unroll
        for (int rt = 0; rt < 4; ++rt)
#pragma unroll
            for (int i = 0; i < 4; ++i)
                rowmax[wid][rt * 16 + lseg * 4 + i] = best[rt][i];
    }
    __syncthreads();
    if (tid < 64) {    // global row max across the 4 waves -> threshold
        float m0 = fmaxf(rowmax[0][tid], rowmax[1][tid]);
        float m1 = fmaxf(rowmax[2][tid], rowmax[3][tid]);
        thrL[tid] = fmaxf(m0, m1) - DELTA;
    }
    __syncthreads();

    f32x4 thr[4];
#pragma unroll
    for (int rt = 0; rt < 4; ++rt)
#pragma unroll
        for (int i = 0; i < 4; ++i) thr[rt][i] = thrL[rt * 16 + lseg * 4 + i];

    // ---- sweep 2: same MFMA; tree-max + one ballot gate, rare push ----
    {
        BT s0, s1, s2, s3;
        loadB(0, s0); loadB(1, s1); loadB(2, s2); loadB(3, s3);
#define S2BODY(SLOT, T)                                                        \
        {                                                                      \
            f32x4 acc[4];                                                      \
            mfmaT(SLOT, acc);                                                  \
            f32x4 d[4];                                                        \
            _Pragma("unroll")                                                  \
            for (int rt = 0; rt < 4; ++rt)                                     \
                _Pragma("unroll")                                              \
                for (int i = 0; i < 4; ++i)                                    \
                    d[rt][i] = acc[rt][i] - thr[rt][i];                        \
            float g0 = fmaxf(fmaxf(fmaxf(d[0][0], d[0][1]), fmaxf(d[0][2], d[0][3])),  \
                             fmaxf(fmaxf(d[1][0], d[1][1]), fmaxf(d[1][2], d[1][3]))); \
            float g1 = fmaxf(fmaxf(fmaxf(d[2][0], d[2][1]), fmaxf(d[2][2], d[2][3])),  \
                             fmaxf(fmaxf(d[3][0], d[3][1]), fmaxf(d[3][2], d[3][3]))); \
            if (__ballot(fmaxf(g0, g1) >= 0.f)) {                              \
                unsigned code = (unsigned)(k0 + (T) * 16 + lrow);              \
                _Pragma("unroll")                                              \
                for (int rt = 0; rt < 4; ++rt)                                 \
                    _Pragma("unroll")                                          \
                    for (int i = 0; i < 4; ++i)                                \
                        if (d[rt][i] >= 0.f) {                                 \
                            unsigned row = (unsigned)(rt * 16 + lseg * 4 + i); \
                            unsigned pos = atomicAdd(&lcnt, 1u);               \
                            if (pos < LISTCAP) list[pos] = (row << 12) | code; \
                        }                                                      \
            }                                                                  \
            loadB((T) + 4 < TILES ? (T) + 4 : 0, SLOT);                        \
        }
        for (int t = 0; t < TILES; t += 4) {
            S2BODY(s0, t + 0)
            S2BODY(s1, t + 1)
            S2BODY(s2, t + 2)
            S2BODY(s3, t + 3)
        }
#undef S2BODY
    }
    __syncthreads();

    // ---- exact fp32 rescore: 4 lanes per candidate (coalesced 256B) ----
    unsigned cnt = lcnt; if (cnt > LISTCAP) cnt = LISTCAP;
    for (unsigned t4 = tid; t4 < cnt * 4; t4 += 256) {
        unsigned t = t4 >> 2; int q = t4 & 3;
        unsigned e = list[t];
        int row = (int)(e >> 12), c = (int)(e & 4095u);
        const float4* xp = reinterpret_cast<const float4*>(enc + (size_t)(pbase + row) * CDIM) + q * 4;
        const float4* ep = reinterpret_cast<const float4*>(cbf + (size_t)c * CDIM) + q * 4;
        float a0 = 0.f, a1 = 0.f, a2 = 0.f, a3 = 0.f;
#pragma unroll
        for (int i = 0; i < 4; ++i) {
            float4 xv = xp[i], ev = ep[i];
            a0 = fmaf(xv.x, ev.x, a0); a1 = fmaf(xv.y, ev.y, a1);
            a2 = fmaf(xv.z, ev.z, a2); a3 = fmaf(xv.w, ev.w, a3);
        }
        float p = (a0 + a1) + (a2 + a3);
        p += __shfl_xor(p, 1, 64);
        p += __shfl_xor(p, 2, 64);               // full dot in all 4 lanes
        if (q == 0) {
            float d2 = fmaf(-2.f, p, 2.f * h[c]);     // esq - 2*dot (bit-identical everywhere)
            unsigned bb = __float_as_uint(d2);
            unsigned ord = bb ^ (unsigned)(((int)bb >> 31) | 0x80000000);  // monotonic
            atomicMin(&mkey[row], ((unsigned long long)ord << 32) | (unsigned)c);
        }
    }
    __syncthreads();

    // ---- finalize: gather winner rows (4 threads per point) + idx ----
    {
        int p = tid >> 2, q = tid & 3;
        int c = (int)(mkey[p] & 4095u);
        const float4* ep = reinterpret_cast<const float4*>(cbf + (size_t)c * CDIM) + q * 4;
        float4* op = reinterpret_cast<float4*>(out + (size_t)(pbase + p) * CDIM) + q * 4;
#pragma unroll
        for (int i = 0; i < 4; ++i) op[i] = ep[i];
        if (tid < 64)
            out[(size_t)NPTS * CDIM + pbase + tid] = (float)(mkey[tid] & 4095u);
    }
}

extern "C" void kernel_launch(void* const* d_in, const int* in_sizes, int n_in,
                              void* d_out, int out_size, void* d_ws, size_t ws_size,
                              hipStream_t stream) {
    const float* enc = (const float*)d_in[0];
    const float* cb  = (const float*)d_in[1];
    float* out = (float*)d_out;

    // ws: cbb bf16[4096*64] (512KB) | h fp32[4096] (16KB)
    short* cbb = (short*)d_ws;
    float* hws = (float*)(cbb + (size_t)KCODES * CDIM);

    vq_prep<<<KCODES / 256, 256, 0, stream>>>(cb, cbb, hws);
    vq_main<<<NPTS / 64, 256, 0, stream>>>(enc, cb, cbb, hws, out);
}